// Round 7
// baseline (126.028 us; speedup 1.0000x reference)
//
#include <hip/hip_runtime.h>

// R23: kill the LDS tile — direct-gather from NHWC4 x in L2 (guide lesson:
// don't LDS-stage what L2 fits; 1.77MB/image fits per-XCD L2 w/ batch swizzle).
// Evidence: scheduling is exhausted (R17 occupancy flat, R21 hoist flat,
// R22 asm-pinned loads flat); only work-removal moved time (R18 -3.5%,
// R20 -10%). Remaining removable work: staging loop + barrier + all ds_reads
// + dual interior/border structure.
// Design: prep_fast transposes x NCHW->NHWC4 into d_ws (18.9MB, ~6-8us,
// also repacks weights); deform_gather reads 9+36 dwordx4/thread from
// L1/L2, no LDS, no barrier, ONE unified path (bad-mask vs whole image,
// pass-B exact fixup; border path deleted). fma4 nesting kept bit-identical
// between pass A and pass B's cancellation term.
// Tiers: ws>=19MB fast | ws>=2.5KB R21-WS | else R18-LDS. Names in profile
// reveal the tier.
// Predicted (fast): deform ->26-34us, LDS_Block_Size=0, total ->96-103.
// Falsifier: fast runs but deform >=40us -> gather dataflow is the floor ->
// structural plateau, revert R20.
//
// Fused: offset = conv3x3(x,w1)+b1 ; out = deform_conv(x, offset, w2)+b2
// x: (8,3,384,384) f32 NCHW ; out: (8,3,382,382) f32

#define BB 8
#define HH 384
#define WW 384
#define HO 382
#define WO 382
#define HW (HH * WW)
#define TW 32
#define TH 8
#define TILES_X 12               // ceil(382/32)
#define TILES_Y 48               // ceil(382/8)
#define SROWS 15                 // rows r0-2 .. r0+12 (fallback tile)
#define SCOLS 39                 // cols w0-2 .. w0+36
#define SSTRIDE 39

// d_ws float offsets
#define WS_W1P 0     // 486 floats: pairs [((j*3+c)*9+k)*2+comp]
#define WS_W2P 512   // 54  floats: pairs (o=0,1) [(k*3+c)*2+o]
#define WS_W2S 576   // 27  floats: scalar o=2   [k*3+c]
#define WS_X4  640   // NHWC4 x: 8*HW*4 floats
#define WS_WEIGHT_FLOATS 640
#define WS_FAST_FLOATS (WS_X4 + 8L * HW * 4)

typedef float v2f __attribute__((ext_vector_type(2), aligned(8)));
typedef float v4f __attribute__((ext_vector_type(4), aligned(16)));

static __device__ __forceinline__ v2f fma2(v2f a, v2f b, v2f c) {
    return __builtin_elementwise_fma(a, b, c);
}
static __device__ __forceinline__ v4f fma4(v4f a, v4f b, v4f c) {
    return __builtin_elementwise_fma(a, b, c);
}
static __device__ __forceinline__ v2f lo2(v4f v) { v2f r; r.x = v.x; r.y = v.y; return r; }
static __device__ __forceinline__ v2f hi2(v4f v) { v2f r; r.x = v.z; r.y = v.w; return r; }
static __device__ __forceinline__ v2f bc2(float f) { v2f r; r.x = f; r.y = f; return r; }
static __device__ __forceinline__ v4f bc4(float f) { v4f r; r.x = f; r.y = f; r.z = f; r.w = f; return r; }

// ============ fast-path prep: weights repack + NCHW->NHWC4 transpose =======
__global__ __launch_bounds__(256) void prep_fast(
    const float* __restrict__ x,
    const float* __restrict__ w1,
    const float* __restrict__ w2,
    float* __restrict__ ws)
{
    const int bid = blockIdx.x;
    if (bid == 0) {
        for (int i = threadIdx.x; i < 486; i += 256) {
            const int oc = i / 27, rem = i % 27, c = rem / 9, j = rem % 9;
            const int k = oc >> 1, comp = oc & 1;
            ws[WS_W1P + ((j * 3 + c) * 9 + k) * 2 + comp] = w1[i];
        }
        if (threadIdx.x < 81) {
            const int i = threadIdx.x;
            const int o = i / 27, c = (i % 27) / 9, k = i % 9;
            if (o < 2) ws[WS_W2P + (k * 3 + c) * 2 + o] = w2[i];
            else       ws[WS_W2S + k * 3 + c] = w2[i];
        }
    }
    // 4608 blocks = 8 images x 576 chunks; batch-per-XCD swizzle
    const int b = bid & 7;
    const int chunk = bid >> 3;            // 0..575
    const int p = chunk * 256 + (int)threadIdx.x;   // 0..147455
    const float* xb = x + (long)b * 3 * HW;
    v4f q;
    q.x = xb[p];
    q.y = xb[p + HW];
    q.z = xb[p + 2 * HW];
    q.w = 0.f;
    *(v4f*)(ws + WS_X4 + ((long)b * HW + p) * 4) = q;
}

// ============ weights-only prep for the mid tier ===========================
__global__ __launch_bounds__(512) void prep_weights(
    const float* __restrict__ w1,
    const float* __restrict__ w2,
    float* __restrict__ ws)
{
    const int i = threadIdx.x;
    if (i < 486) {
        const int oc = i / 27, rem = i % 27, c = rem / 9, j = rem % 9;
        const int k = oc >> 1, comp = oc & 1;
        ws[WS_W1P + ((j * 3 + c) * 9 + k) * 2 + comp] = w1[i];
    }
    if (i < 81) {
        const int o = i / 27, c = (i % 27) / 9, k = i % 9;
        if (o < 2) ws[WS_W2P + (k * 3 + c) * 2 + o] = w2[i];
        else       ws[WS_W2S + k * 3 + c] = w2[i];
    }
}

// ============ fast path: no LDS, no barrier, unified mask+fixup ============
__global__ __launch_bounds__(256, 4) void deform_gather(
    const float* __restrict__ x,      // NCHW, pass-B exact path only
    const float* __restrict__ b1,
    const float* __restrict__ b2,
    const float* __restrict__ wsp,
    float* __restrict__ out)
{
    const v2f*   __restrict__ w1p = (const v2f*)(wsp + WS_W1P);  // uniform
    const v2f*   __restrict__ w2p = (const v2f*)(wsp + WS_W2P);
    const float* __restrict__ w2s = wsp + WS_W2S;

    const int b  = blockIdx.x & 7;            // batch per XCD (L2 locality)
    const int t  = blockIdx.x >> 3;
    const int tx = t % TILES_X;
    const int ty = t / TILES_X;
    const int wo = tx * TW + (int)(threadIdx.x & 31);
    const int ho = ty * TH + (int)(threadIdx.x >> 5);
    if (wo >= WO || ho >= HO) return;

    const v4f* __restrict__ xq = (const v4f*)(wsp + WS_X4) + (long)b * HW;
    const float* xp0 = x + (long)b * 3 * HW;
    const float* xp1 = xp0 + HW;
    const float* xp2 = xp0 + 2 * HW;

    // ---- Phase 1: offsets from 9 NHWC4 pixels + SGPR weight pairs ----
    v2f off2[9];
    const v2f* __restrict__ b1p = (const v2f*)b1;   // uniform -> s_load
#pragma unroll
    for (int k = 0; k < 9; ++k) off2[k] = b1p[k];

#pragma unroll
    for (int i = 0; i < 3; ++i) {
        const int rb = (ho + i) * WW + wo;
        const v4f qa = xq[rb];        // pixel (ho+i, wo+0)
        const v4f qb = xq[rb + 1];    // (ho+i, wo+1)
        const v4f qc = xq[rb + 2];    // (ho+i, wo+2)
        const float xs0[3] = { qa.x, qa.y, qa.z };
        const float xs1[3] = { qb.x, qb.y, qb.z };
        const float xs2[3] = { qc.x, qc.y, qc.z };
#pragma unroll
        for (int jj = 0; jj < 3; ++jj) {
            const int j = i * 3 + jj;
#pragma unroll
            for (int c = 0; c < 3; ++c) {
                const float xc = (jj == 0) ? xs0[c] : (jj == 1) ? xs1[c] : xs2[c];
                const v2f xcv = bc2(xc);
                const v2f* wrow = w1p + (j * 3 + c) * 9;
#pragma unroll
                for (int k = 0; k < 9; ++k)
                    off2[k] = fma2(xcv, wrow[k], off2[k]);
            }
        }
    }

    // ---- Phase 2, stage 1: all 9 taps' addr+fraction vs WHOLE image ----
    float acc0 = b2[0], acc1 = b2[1], acc2 = b2[2];  // uniform -> s_load
    unsigned bad = 0u;
    int pv[9];
    v2f frv[9];
#pragma unroll
    for (int k = 0; k < 9; ++k) {
        const int kh = k / 3, kw = k - kh * 3;
        v2f pos; pos.x = (float)(ho + kh); pos.y = (float)(wo + kw);
        pos += off2[k];
        const v2f fl = __builtin_elementwise_floor(pos);
        frv[k] = pos - fl;
        const int y0 = (int)fl.x;
        const int x0 = (int)fl.y;
        bad |= (((unsigned)y0 > (unsigned)(HH - 2)) |
                ((unsigned)x0 > (unsigned)(WW - 2))) ? (1u << k) : 0u;
        const int cy = min(max(y0, 0), HH - 2);
        const int cx = min(max(x0, 0), WW - 2);
        pv[k] = cy * WW + cx;
    }

    // ---- Phase 2, stage 2: dep-free NHWC4 gathers + bilinear + accum ----
#pragma unroll
    for (int k = 0; k < 9; ++k) {
        const v4f* p0 = xq + pv[k];
        const v4f q00 = p0[0], q01 = p0[1];
        const v4f q10 = p0[WW], q11 = p0[WW + 1];

        const v2f fr = frv[k];
        const float g00 = (1.f - fr.x) * (1.f - fr.y);
        const float g01 = (1.f - fr.x) * fr.y;
        const float g10 = fr.x * (1.f - fr.y);
        const float g11 = fr.x * fr.y;

        v4f t4 = bc4(g00) * q00;
        t4 = fma4(bc4(g01), q01, t4);
        t4 = fma4(bc4(g10), q10, t4);
        t4 = fma4(bc4(g11), q11, t4);
        const float v0 = t4.x, v1 = t4.y, v2v = t4.z;

        v2f acc01; acc01.x = acc0; acc01.y = acc1;
        acc01 = fma2(bc2(v0),  w2p[k * 3 + 0], acc01);
        acc01 = fma2(bc2(v1),  w2p[k * 3 + 1], acc01);
        acc01 = fma2(bc2(v2v), w2p[k * 3 + 2], acc01);
        acc0 = acc01.x; acc1 = acc01.y;
        acc2 = fmaf(w2s[k * 3 + 0], v0, acc2);
        acc2 = fmaf(w2s[k * 3 + 1], v1, acc2);
        acc2 = fmaf(w2s[k * 3 + 2], v2v, acc2);
    }

    // ---- Pass B: exact fixup for out-of-image taps (rare, execz) ----
    if (bad) {
#pragma unroll 1
        for (int k = 0; k < 9; ++k) {
            if ((bad >> k) & 1u) {
                const int kh = k / 3, kw = k - kh * 3;
                v2f pos; pos.x = (float)(ho + kh); pos.y = (float)(wo + kw);
                pos += off2[k];
                const v2f fl = __builtin_elementwise_floor(pos);
                const v2f fr = pos - fl;
                const int y0 = (int)fl.x;
                const int x0 = (int)fl.y;

                // -- wrong contribution: EXACT replay of stage-2 ops --
                const int cy = min(max(y0, 0), HH - 2);
                const int cx = min(max(x0, 0), WW - 2);
                const v4f* p0 = xq + (cy * WW + cx);
                const v4f w00 = p0[0], w01 = p0[1];
                const v4f w10 = p0[WW], w11 = p0[WW + 1];
                const float a00 = (1.f - fr.x) * (1.f - fr.y);
                const float a01 = (1.f - fr.x) * fr.y;
                const float a10 = fr.x * (1.f - fr.y);
                const float a11 = fr.x * fr.y;
                v4f tw = bc4(a00) * w00;
                tw = fma4(bc4(a01), w01, tw);
                tw = fma4(bc4(a10), w10, tw);
                tw = fma4(bc4(a11), w11, tw);

                // -- right contribution (exact reference semantics) --
                const int ry0 = min(max(y0, 0), HH - 1);
                const int ry1 = min(max(y0 + 1, 0), HH - 1);
                const int xbs = min(max(x0, 0), WW - 2);
                const bool vy0 = (y0 >= 0) & (y0 <= HH - 1);
                const bool vy1 = (y0 >= -1) & (y0 <= HH - 2);
                const bool vx0 = (x0 >= 0) & (x0 <= WW - 1);
                const bool vx1 = (x0 >= -1) & (x0 <= WW - 2);
                const float wy0m = vy0 ? (1.f - fr.x) : 0.f;
                const float wy1m = vy1 ? fr.x : 0.f;
                const float wx0m = vx0 ? (1.f - fr.y) : 0.f;
                const float wx1m = vx1 ? fr.y : 0.f;
                const bool selA = (x0 >= WW - 1);
                const bool selB = (x0 >= 0);
                const float e0 = (selA ? 0.f : wx0m) + (selB ? 0.f : wx1m);
                const float e1 = (selA ? wx0m : 0.f) + (selB ? wx1m : 0.f);
                const float g00 = wy0m * e0, g01 = wy0m * e1;
                const float g10 = wy1m * e0, g11 = wy1m * e1;
                const int o0 = ry0 * WW + xbs;
                const int o1 = ry1 * WW + xbs;
                v4f r0g, r1g, r2g, r3g;
                r0g.x = xp0[o0];     r0g.y = xp1[o0];     r0g.z = xp2[o0];     r0g.w = 0.f;
                r1g.x = xp0[o0 + 1]; r1g.y = xp1[o0 + 1]; r1g.z = xp2[o0 + 1]; r1g.w = 0.f;
                r2g.x = xp0[o1];     r2g.y = xp1[o1];     r2g.z = xp2[o1];     r2g.w = 0.f;
                r3g.x = xp0[o1 + 1]; r3g.y = xp1[o1 + 1]; r3g.z = xp2[o1 + 1]; r3g.w = 0.f;
                v4f tr = bc4(g00) * r0g;
                tr = fma4(bc4(g01), r1g, tr);
                tr = fma4(bc4(g10), r2g, tr);
                tr = fma4(bc4(g11), r3g, tr);

                const float d0 = tr.x - tw.x;
                const float d1 = tr.y - tw.y;
                const float d2 = tr.z - tw.z;

                v2f acc01; acc01.x = acc0; acc01.y = acc1;
                acc01 = fma2(bc2(d0), w2p[k * 3 + 0], acc01);
                acc01 = fma2(bc2(d1), w2p[k * 3 + 1], acc01);
                acc01 = fma2(bc2(d2), w2p[k * 3 + 2], acc01);
                acc0 = acc01.x; acc1 = acc01.y;
                acc2 = fmaf(w2s[k * 3 + 0], d0, acc2);
                acc2 = fmaf(w2s[k * 3 + 1], d1, acc2);
                acc2 = fmaf(w2s[k * 3 + 2], d2, acc2);
            }
        }
    }

    const long obase = ((long)(b * 3) * HO + ho) * WO + wo;
    __builtin_nontemporal_store(acc0, out + obase);
    __builtin_nontemporal_store(acc1, out + obase + (long)HO * WO);
    __builtin_nontemporal_store(acc2, out + obase + 2L * HO * WO);
}

// ============ fallback tiers: R21 tiled kernel (proven ~R20 perf) ==========
template<bool USE_WS>
__global__ __launch_bounds__(256, 4) void deform_tiled(
    const float* __restrict__ x,
    const float* __restrict__ w1,
    const float* __restrict__ b1,
    const float* __restrict__ w2,
    const float* __restrict__ b2,
    const float* __restrict__ wsp,
    float* __restrict__ out)
{
    __shared__ v4f  s_p01[SROWS * SSTRIDE];
    __shared__ v2f  s_p2 [SROWS * SSTRIDE];
    __shared__ float s_w1p[486];
    __shared__ float s_w2p[54];
    __shared__ float s_w2s[27];

    if constexpr (!USE_WS) {
        for (int i = threadIdx.x; i < 486; i += 256) {
            const int oc = i / 27, rem = i % 27, c = rem / 9, j = rem % 9;
            const int k = oc >> 1, comp = oc & 1;
            s_w1p[((j * 3 + c) * 9 + k) * 2 + comp] = w1[i];
        }
        if (threadIdx.x < 81) {
            const int i = threadIdx.x;
            const int o = i / 27, c = (i % 27) / 9, k = i % 9;
            if (o < 2) s_w2p[(k * 3 + c) * 2 + o] = w2[i];
            else       s_w2s[k * 3 + c] = w2[i];
        }
    }

    const v2f*   __restrict__ w1p;
    const v2f*   __restrict__ w2p;
    const float* __restrict__ w2s;
    if constexpr (USE_WS) {
        w1p = (const v2f*)(wsp + WS_W1P);
        w2p = (const v2f*)(wsp + WS_W2P);
        w2s = wsp + WS_W2S;
    } else {
        w1p = (const v2f*)s_w1p;
        w2p = (const v2f*)s_w2p;
        w2s = s_w2s;
    }

    const int b  = blockIdx.x & 7;
    const int t  = blockIdx.x >> 3;
    const int tx = t % TILES_X;
    const int ty = t / TILES_X;
    const int w0 = tx * TW;
    const int r0 = ty * TH;

    const float* xp0 = x + (long)b * 3 * HW;
    const float* xp1 = xp0 + HW;
    const float* xp2 = xp0 + 2 * HW;

    const int gr0 = r0 - 2, gc0 = w0 - 2;
    for (int s = threadIdx.x; s < SROWS * SCOLS; s += 256) {
        const int sr = s / SCOLS, sc = s - sr * SCOLS;
        const int gy = min(max(gr0 + sr, 0), HH - 1);
        const int gx = min(max(gc0 + sc, 0), WW - 1);
        const int base = gy * WW + gx;
        const float c0 = xp0[base];
        const float c1 = xp1[base];
        const float c2 = xp2[base];
        v2f p; p.x = c0; p.y = c1;
        const int e = sr * SSTRIDE + sc;
        *(v2f*)(&s_p01[e]) = p;
        s_p2[e].x = c2;
        if (sc > 0) {
            *((v2f*)(&s_p01[e - 1]) + 1) = p;
            s_p2[e - 1].y = c2;
        }
    }
    __syncthreads();

    const int wo_in = threadIdx.x & 31;
    const int ho_in = threadIdx.x >> 5;
    const int wo = w0 + wo_in;
    const int ho = r0 + ho_in;
    if (wo >= WO || ho >= HO) return;

    v2f off2[9];
    const v2f* __restrict__ b1p = (const v2f*)b1;
#pragma unroll
    for (int k = 0; k < 9; ++k) off2[k] = b1p[k];

    const int pc = wo_in + 2;
#pragma unroll
    for (int i = 0; i < 3; ++i) {
        const int rowb = (ho_in + 2 + i) * SSTRIDE + pc;
        const v4f pa = s_p01[rowb];
        const v4f pb = s_p01[rowb + 2];
        const v2f sa = s_p2[rowb];
        const v2f sb = s_p2[rowb + 2];
        const float xs0[3] = { pa.x, pa.y, sa.x };
        const float xs1[3] = { pa.z, pa.w, sa.y };
        const float xs2[3] = { pb.x, pb.y, sb.x };
#pragma unroll
        for (int jj = 0; jj < 3; ++jj) {
            const int j = i * 3 + jj;
#pragma unroll
            for (int c = 0; c < 3; ++c) {
                const float xc = (jj == 0) ? xs0[c] : (jj == 1) ? xs1[c] : xs2[c];
                const v2f xcv = bc2(xc);
                const v2f* wrow = w1p + (j * 3 + c) * 9;
#pragma unroll
                for (int k = 0; k < 9; ++k)
                    off2[k] = fma2(xcv, wrow[k], off2[k]);
            }
        }
    }

    float acc0 = b2[0], acc1 = b2[1], acc2 = b2[2];

    const bool interior = (gr0 >= 0) & (gc0 >= 0) &
                          (gr0 + SROWS <= HH) & (gc0 + SCOLS <= WW);

    if (interior) {
        unsigned bad = 0u;
        int ibv[9];
        v2f frv[9];
#pragma unroll
        for (int k = 0; k < 9; ++k) {
            const int kh = k / 3, kw = k - kh * 3;
            v2f pos; pos.x = (float)(ho + kh); pos.y = (float)(wo + kw);
            pos += off2[k];
            const v2f fl = __builtin_elementwise_floor(pos);
            frv[k] = pos - fl;
            const int y0 = (int)fl.x;
            const int x0 = (int)fl.y;
            const int ly0 = y0 - gr0;
            const int lx  = x0 - gc0;
            bad |= (((unsigned)ly0 > (unsigned)(SROWS - 2)) |
                    ((unsigned)lx  > (unsigned)(SCOLS - 2))) ? (1u << k) : 0u;
            const int cy0 = min(max(ly0, 0), SROWS - 2);
            const int cx  = min(max(lx, 0),  SCOLS - 2);
            ibv[k] = cy0 * SSTRIDE + cx;
        }

#pragma unroll
        for (int k = 0; k < 9; ++k) {
            const int ib = ibv[k];
            const v4f r0v = s_p01[ib];
            const v4f r1v = s_p01[ib + SSTRIDE];
            const v2f s0v = s_p2[ib];
            const v2f s1v = s_p2[ib + SSTRIDE];
            const v2f fr = frv[k];
            const float g00 = (1.f - fr.x) * (1.f - fr.y);
            const float g01 = (1.f - fr.x) * fr.y;
            const float g10 = fr.x * (1.f - fr.y);
            const float g11 = fr.x * fr.y;
            v2f t01 = bc2(g00) * lo2(r0v);
            t01 = fma2(bc2(g01), hi2(r0v), t01);
            t01 = fma2(bc2(g10), lo2(r1v), t01);
            t01 = fma2(bc2(g11), hi2(r1v), t01);
            float t2 = g00 * s0v.x;
            t2 = fmaf(g01, s0v.y, t2);
            t2 = fmaf(g10, s1v.x, t2);
            t2 = fmaf(g11, s1v.y, t2);
            const float v0 = t01.x, v1 = t01.y, v2v = t2;
            v2f acc01; acc01.x = acc0; acc01.y = acc1;
            acc01 = fma2(bc2(v0),  w2p[k * 3 + 0], acc01);
            acc01 = fma2(bc2(v1),  w2p[k * 3 + 1], acc01);
            acc01 = fma2(bc2(v2v), w2p[k * 3 + 2], acc01);
            acc0 = acc01.x; acc1 = acc01.y;
            acc2 = fmaf(w2s[k * 3 + 0], v0, acc2);
            acc2 = fmaf(w2s[k * 3 + 1], v1, acc2);
            acc2 = fmaf(w2s[k * 3 + 2], v2v, acc2);
        }

        if (bad) {
#pragma unroll 1
            for (int k = 0; k < 9; ++k) {
                if ((bad >> k) & 1u) {
                    const int kh = k / 3, kw = k - kh * 3;
                    v2f pos; pos.x = (float)(ho + kh); pos.y = (float)(wo + kw);
                    pos += off2[k];
                    const v2f fl = __builtin_elementwise_floor(pos);
                    const v2f fr = pos - fl;
                    const int y0 = (int)fl.x;
                    const int x0 = (int)fl.y;
                    const int ly0 = y0 - gr0;
                    const int lx  = x0 - gc0;
                    const float a00 = (1.f - fr.x) * (1.f - fr.y);
                    const float a01 = (1.f - fr.x) * fr.y;
                    const float a10 = fr.x * (1.f - fr.y);
                    const float a11 = fr.x * fr.y;
                    const int cy0 = min(max(ly0, 0), SROWS - 2);
                    const int cx  = min(max(lx, 0),  SCOLS - 2);
                    const int ib  = cy0 * SSTRIDE + cx;
                    const v4f r0v = s_p01[ib];
                    const v4f r1v = s_p01[ib + SSTRIDE];
                    const v2f s0v = s_p2[ib];
                    const v2f s1v = s_p2[ib + SSTRIDE];
                    v2f tw01 = bc2(a00) * lo2(r0v);
                    tw01 = fma2(bc2(a01), hi2(r0v), tw01);
                    tw01 = fma2(bc2(a10), lo2(r1v), tw01);
                    tw01 = fma2(bc2(a11), hi2(r1v), tw01);
                    float tw2 = a00 * s0v.x;
                    tw2 = fmaf(a01, s0v.y, tw2);
                    tw2 = fmaf(a10, s1v.x, tw2);
                    tw2 = fmaf(a11, s1v.y, tw2);

                    const int ry0 = min(max(y0, 0), HH - 1);
                    const int ry1 = min(max(y0 + 1, 0), HH - 1);
                    const int xbs = min(max(x0, 0), WW - 2);
                    const bool vy0 = (y0 >= 0) & (y0 <= HH - 1);
                    const bool vy1 = (y0 >= -1) & (y0 <= HH - 2);
                    const bool vx0 = (x0 >= 0) & (x0 <= WW - 1);
                    const bool vx1 = (x0 >= -1) & (x0 <= WW - 2);
                    const float wy0m = vy0 ? (1.f - fr.x) : 0.f;
                    const float wy1m = vy1 ? fr.x : 0.f;
                    const float wx0m = vx0 ? (1.f - fr.y) : 0.f;
                    const float wx1m = vx1 ? fr.y : 0.f;
                    const bool selA = (x0 >= WW - 1);
                    const bool selB = (x0 >= 0);
                    const float e0 = (selA ? 0.f : wx0m) + (selB ? 0.f : wx1m);
                    const float e1 = (selA ? wx0m : 0.f) + (selB ? wx1m : 0.f);
                    const float g00 = wy0m * e0, g01 = wy0m * e1;
                    const float g10 = wy1m * e0, g11 = wy1m * e1;
                    const int o0 = ry0 * WW + xbs;
                    const int o1 = ry1 * WW + xbs;
                    v4f r0g, r1g; v2f s0g, s1g;
                    r0g.x = xp0[o0];     r0g.y = xp1[o0];
                    r0g.z = xp0[o0 + 1]; r0g.w = xp1[o0 + 1];
                    s0g.x = xp2[o0];     s0g.y = xp2[o0 + 1];
                    r1g.x = xp0[o1];     r1g.y = xp1[o1];
                    r1g.z = xp0[o1 + 1]; r1g.w = xp1[o1 + 1];
                    s1g.x = xp2[o1];     s1g.y = xp2[o1 + 1];
                    v2f tr01 = bc2(g00) * lo2(r0g);
                    tr01 = fma2(bc2(g01), hi2(r0g), tr01);
                    tr01 = fma2(bc2(g10), lo2(r1g), tr01);
                    tr01 = fma2(bc2(g11), hi2(r1g), tr01);
                    float tr2 = g00 * s0g.x;
                    tr2 = fmaf(g01, s0g.y, tr2);
                    tr2 = fmaf(g10, s1g.x, tr2);
                    tr2 = fmaf(g11, s1g.y, tr2);

                    const float d0 = tr01.x - tw01.x;
                    const float d1 = tr01.y - tw01.y;
                    const float d2 = tr2 - tw2;

                    v2f acc01; acc01.x = acc0; acc01.y = acc1;
                    acc01 = fma2(bc2(d0), w2p[k * 3 + 0], acc01);
                    acc01 = fma2(bc2(d1), w2p[k * 3 + 1], acc01);
                    acc01 = fma2(bc2(d2), w2p[k * 3 + 2], acc01);
                    acc0 = acc01.x; acc1 = acc01.y;
                    acc2 = fmaf(w2s[k * 3 + 0], d0, acc2);
                    acc2 = fmaf(w2s[k * 3 + 1], d1, acc2);
                    acc2 = fmaf(w2s[k * 3 + 2], d2, acc2);
                }
            }
        }
    } else {
#pragma unroll 1
        for (int k = 0; k < 9; ++k) {
            const int kh = k / 3, kw = k - kh * 3;
            v2f pos; pos.x = (float)(ho + kh); pos.y = (float)(wo + kw);
            pos += off2[k];
            const v2f fl = __builtin_elementwise_floor(pos);
            const v2f fr = pos - fl;
            const int y0 = (int)fl.x;
            const int x0 = (int)fl.y;

            const int ry0 = min(max(y0, 0), HH - 1);
            const int ry1 = min(max(y0 + 1, 0), HH - 1);
            const int xbs = min(max(x0, 0), WW - 2);
            const bool vy0 = (y0 >= 0) & (y0 <= HH - 1);
            const bool vy1 = (y0 >= -1) & (y0 <= HH - 2);
            const bool vx0 = (x0 >= 0) & (x0 <= WW - 1);
            const bool vx1 = (x0 >= -1) & (x0 <= WW - 2);
            const float wy0m = vy0 ? (1.f - fr.x) : 0.f;
            const float wy1m = vy1 ? fr.x : 0.f;
            const float wx0m = vx0 ? (1.f - fr.y) : 0.f;
            const float wx1m = vx1 ? fr.y : 0.f;
            const bool selA = (x0 >= WW - 1);
            const bool selB = (x0 >= 0);
            const float e0 = (selA ? 0.f : wx0m) + (selB ? 0.f : wx1m);
            const float e1 = (selA ? wx0m : 0.f) + (selB ? wx1m : 0.f);
            const float g00 = wy0m * e0, g01 = wy0m * e1;
            const float g10 = wy1m * e0, g11 = wy1m * e1;

            const int ly0 = ry0 - gr0;
            const int ly1 = ry1 - gr0;
            const int lx  = xbs - gc0;
            const bool inTile = ((unsigned)ly0 <= SROWS - 1) &
                                ((unsigned)ly1 <= SROWS - 1) &
                                ((unsigned)lx  <= SCOLS - 2);
            const int cy0 = min(max(ly0, 0), SROWS - 1);
            const int cy1 = min(max(ly1, 0), SROWS - 1);
            const int cx  = min(max(lx, 0),  SCOLS - 2);
            const int ib0 = cy0 * SSTRIDE + cx;
            const int ib1 = cy1 * SSTRIDE + cx;
            v4f r0v = s_p01[ib0];
            v4f r1v = s_p01[ib1];
            v2f s0v = s_p2[ib0];
            v2f s1v = s_p2[ib1];
            if (!inTile) {
                const int o0 = ry0 * WW + xbs;
                const int o1 = ry1 * WW + xbs;
                r0v.x = xp0[o0];     r0v.y = xp1[o0];
                r0v.z = xp0[o0 + 1]; r0v.w = xp1[o0 + 1];
                s0v.x = xp2[o0];     s0v.y = xp2[o0 + 1];
                r1v.x = xp0[o1];     r1v.y = xp1[o1];
                r1v.z = xp0[o1 + 1]; r1v.w = xp1[o1 + 1];
                s1v.x = xp2[o1];     s1v.y = xp2[o1 + 1];
            }
            v2f t01 = bc2(g00) * lo2(r0v);
            t01 = fma2(bc2(g01), hi2(r0v), t01);
            t01 = fma2(bc2(g10), lo2(r1v), t01);
            t01 = fma2(bc2(g11), hi2(r1v), t01);
            float t2 = g00 * s0v.x;
            t2 = fmaf(g01, s0v.y, t2);
            t2 = fmaf(g10, s1v.x, t2);
            t2 = fmaf(g11, s1v.y, t2);
            const float v0 = t01.x, v1 = t01.y, v2v = t2;
            v2f acc01; acc01.x = acc0; acc01.y = acc1;
            acc01 = fma2(bc2(v0),  w2p[k * 3 + 0], acc01);
            acc01 = fma2(bc2(v1),  w2p[k * 3 + 1], acc01);
            acc01 = fma2(bc2(v2v), w2p[k * 3 + 2], acc01);
            acc0 = acc01.x; acc1 = acc01.y;
            acc2 = fmaf(w2s[k * 3 + 0], v0, acc2);
            acc2 = fmaf(w2s[k * 3 + 1], v1, acc2);
            acc2 = fmaf(w2s[k * 3 + 2], v2v, acc2);
        }
    }

    const long obase = ((long)(b * 3) * HO + ho) * WO + wo;
    __builtin_nontemporal_store(acc0, out + obase);
    __builtin_nontemporal_store(acc1, out + obase + (long)HO * WO);
    __builtin_nontemporal_store(acc2, out + obase + 2L * HO * WO);
}

extern "C" void kernel_launch(void* const* d_in, const int* in_sizes, int n_in,
                              void* d_out, int out_size, void* d_ws, size_t ws_size,
                              hipStream_t stream) {
    const float* x  = (const float*)d_in[0];
    const float* w1 = (const float*)d_in[1];
    const float* b1 = (const float*)d_in[2];
    const float* w2 = (const float*)d_in[3];
    const float* b2 = (const float*)d_in[4];
    float* out = (float*)d_out;
    float* ws  = (float*)d_ws;

    const int blocks = TILES_X * TILES_Y * BB;   // 12*48*8 = 4608

    if (ws != nullptr && ws_size >= (size_t)WS_FAST_FLOATS * sizeof(float)) {
        prep_fast<<<4608, 256, 0, stream>>>(x, w1, w2, ws);
        deform_gather<<<blocks, 256, 0, stream>>>(x, b1, b2, ws, out);
    } else if (ws != nullptr && ws_size >= (size_t)WS_WEIGHT_FLOATS * sizeof(float)) {
        prep_weights<<<1, 512, 0, stream>>>(w1, w2, ws);
        deform_tiled<true><<<blocks, 256, 0, stream>>>(x, w1, b1, w2, b2, ws, out);
    } else {
        deform_tiled<false><<<blocks, 256, 0, stream>>>(x, w1, b1, w2, b2, nullptr, out);
    }
}

// Round 8
// 103.972 us; speedup vs baseline: 1.2121x; 1.2121x over previous
//
#include <hip/hip_runtime.h>

// R24 FINAL = R20 revert (best measured: total 104.5us, deform ~40us).
// Session conclusion: STRUCTURAL PLATEAU at ~40us kernel.
//   Evidence ladder (this session): R17 occupancy 47->55% flat (TLP out);
//   R18 split-plane LDS -25% bytes = -3.5%; R20 weights->SGPR (-165
//   ds_read/thread) = -10% (BEST); R21 source hoist flat (scheduler
//   re-sinks); R22 asm-pinned ds_read batches flat; R23 no-LDS L2 gather
//   +35% WORSE (VMEM latency > LDS latency; staging vindicated).
//   Constraint arithmetic: VALU issue ~20us (phase-1 FMA floor 7us; no
//   fp32 MFMA on CDNA4) + LDS ~15us, ~50% overlap -> ~40us. Scheduling
//   levers exhausted at source AND asm level; only work-removal moved time
//   and the removable work is gone. Remaining lever (bf16/MFMA phase-1)
//   risks absmax for uncertain gain.
//
// Fused: offset = conv3x3(x,w1)+b1 ; out = deform_conv(x, offset, w2)+b2
// x: (8,3,384,384) f32 NCHW ; out: (8,3,382,382) f32
// Structure: 1-block prep repacks w1/w2 pair-interleaves into d_ws (read
// via uniform s_load -> SGPR pk-FMA operands); main kernel stages a
// 15x39 halo tile in split-plane duplicated-pair LDS layout; phase-1
// computes 9 offset pairs; phase-2 pass A = branchless clamped bilinear
// w/ bad-mask, pass B = exact execz-skipped fixup; border blocks take a
// rolled exact path. Batch-per-XCD blockIdx swizzle for L2 locality.

#define BB 8
#define HH 384
#define WW 384
#define HO 382
#define WO 382
#define HW (HH * WW)
#define TW 32
#define TH 8
#define TILES_X 12               // ceil(382/32)
#define TILES_Y 48               // ceil(382/8)
#define SROWS 15                 // rows r0-2 .. r0+12
#define SCOLS 39                 // cols w0-2 .. w0+36
#define SSTRIDE 39

// d_ws float offsets (only used when ws_size permits)
#define WS_W1P 0     // 486 floats: pairs [((j*3+c)*9+k)*2+comp]
#define WS_W2P 512   // 54  floats: pairs (o=0,1) [(k*3+c)*2+o]
#define WS_W2S 576   // 27  floats: scalar o=2   [k*3+c]
#define WS_FLOATS 640

typedef float v2f __attribute__((ext_vector_type(2), aligned(8)));
typedef float v4f __attribute__((ext_vector_type(4), aligned(16)));

static __device__ __forceinline__ v2f fma2(v2f a, v2f b, v2f c) {
    return __builtin_elementwise_fma(a, b, c);
}
static __device__ __forceinline__ v2f lo2(v4f v) { v2f r; r.x = v.x; r.y = v.y; return r; }
static __device__ __forceinline__ v2f hi2(v4f v) { v2f r; r.x = v.z; r.y = v.w; return r; }
static __device__ __forceinline__ v2f bc2(float f) { v2f r; r.x = f; r.y = f; return r; }

__global__ __launch_bounds__(512) void prep_weights(
    const float* __restrict__ w1,
    const float* __restrict__ w2,
    float* __restrict__ ws)
{
    const int i = threadIdx.x;
    if (i < 486) {
        const int oc = i / 27, rem = i % 27, c = rem / 9, j = rem % 9;
        const int k = oc >> 1, comp = oc & 1;
        ws[WS_W1P + ((j * 3 + c) * 9 + k) * 2 + comp] = w1[i];
    }
    if (i < 81) {
        const int o = i / 27, c = (i % 27) / 9, k = i % 9;
        if (o < 2) ws[WS_W2P + (k * 3 + c) * 2 + o] = w2[i];
        else       ws[WS_W2S + k * 3 + c] = w2[i];
    }
}

template<bool USE_WS>
__global__ __launch_bounds__(256, 4) void deform_tiled(
    const float* __restrict__ x,
    const float* __restrict__ w1,
    const float* __restrict__ b1,
    const float* __restrict__ w2,
    const float* __restrict__ b2,
    const float* __restrict__ wsp,
    float* __restrict__ out)
{
    __shared__ v4f  s_p01[SROWS * SSTRIDE];  // {c0[c],c1[c],c0[c+1],c1[c+1]} 9360B
    __shared__ v2f  s_p2 [SROWS * SSTRIDE];  // {c2[c],c2[c+1]}               4680B
    __shared__ float s_w1p[486];             // fallback only
    __shared__ float s_w2p[54];
    __shared__ float s_w2s[27];

    if constexpr (!USE_WS) {
        for (int i = threadIdx.x; i < 486; i += 256) {
            const int oc = i / 27, rem = i % 27, c = rem / 9, j = rem % 9;
            const int k = oc >> 1, comp = oc & 1;
            s_w1p[((j * 3 + c) * 9 + k) * 2 + comp] = w1[i];
        }
        if (threadIdx.x < 81) {
            const int i = threadIdx.x;
            const int o = i / 27, c = (i % 27) / 9, k = i % 9;
            if (o < 2) s_w2p[(k * 3 + c) * 2 + o] = w2[i];
            else       s_w2s[k * 3 + c] = w2[i];
        }
    }

    const v2f*   __restrict__ w1p;
    const v2f*   __restrict__ w2p;
    const float* __restrict__ w2s;
    if constexpr (USE_WS) {
        w1p = (const v2f*)(wsp + WS_W1P);
        w2p = (const v2f*)(wsp + WS_W2P);
        w2s = wsp + WS_W2S;
    } else {
        w1p = (const v2f*)s_w1p;
        w2p = (const v2f*)s_w2p;
        w2s = s_w2s;
    }

    const int b  = blockIdx.x & 7;            // XCD-locality: batch per XCD
    const int t  = blockIdx.x >> 3;
    const int tx = t % TILES_X;
    const int ty = t / TILES_X;
    const int w0 = tx * TW;
    const int r0 = ty * TH;

    const float* xp0 = x + (long)b * 3 * HW;
    const float* xp1 = xp0 + HW;
    const float* xp2 = xp0 + 2 * HW;

    // ---- stage halo tile: 3 global loads/entry, scatter halves into the
    //      duplicated-pair planes (own .xy/.x, left neighbor's .zw/.y) ----
    const int gr0 = r0 - 2, gc0 = w0 - 2;
    for (int s = threadIdx.x; s < SROWS * SCOLS; s += 256) {
        const int sr = s / SCOLS, sc = s - sr * SCOLS;
        const int gy = min(max(gr0 + sr, 0), HH - 1);
        const int gx = min(max(gc0 + sc, 0), WW - 1);
        const int base = gy * WW + gx;
        const float c0 = xp0[base];
        const float c1 = xp1[base];
        const float c2 = xp2[base];
        v2f p; p.x = c0; p.y = c1;
        const int e = sr * SSTRIDE + sc;
        *(v2f*)(&s_p01[e]) = p;                     // entry e, cols {c}
        s_p2[e].x = c2;
        if (sc > 0) {
            *((v2f*)(&s_p01[e - 1]) + 1) = p;       // entry e-1, col {c} as c+1
            s_p2[e - 1].y = c2;
        }
    }
    __syncthreads();

    const int wo_in = threadIdx.x & 31;
    const int ho_in = threadIdx.x >> 5;
    const int wo = w0 + wo_in;
    const int ho = r0 + ho_in;
    if (wo >= WO || ho >= HO) return;         // after the only barrier

    // ---- Phase 1: 9 (dy,dx) pairs; x from LDS tile, w1 pairs uniform ----
    v2f off2[9];
    const v2f* __restrict__ b1p = (const v2f*)b1;   // uniform idx -> s_load
#pragma unroll
    for (int k = 0; k < 9; ++k) off2[k] = b1p[k];

    const int pc = wo_in + 2;
#pragma unroll
    for (int i = 0; i < 3; ++i) {
        const int rowb = (ho_in + 2 + i) * SSTRIDE + pc;
        const v4f pa = s_p01[rowb];       // c01 @ jj=0,1
        const v4f pb = s_p01[rowb + 2];   // c01 @ jj=2 (+waste)
        const v2f sa = s_p2[rowb];        // c2  @ jj=0,1
        const v2f sb = s_p2[rowb + 2];    // c2  @ jj=2 (+waste)
        const float xs0[3] = { pa.x, pa.y, sa.x };
        const float xs1[3] = { pa.z, pa.w, sa.y };
        const float xs2[3] = { pb.x, pb.y, sb.x };
#pragma unroll
        for (int jj = 0; jj < 3; ++jj) {
            const int j = i * 3 + jj;
#pragma unroll
            for (int c = 0; c < 3; ++c) {
                const float xc = (jj == 0) ? xs0[c] : (jj == 1) ? xs1[c] : xs2[c];
                const v2f xcv = bc2(xc);
                const v2f* wrow = w1p + (j * 3 + c) * 9;
#pragma unroll
                for (int k = 0; k < 9; ++k)
                    off2[k] = fma2(xcv, wrow[k], off2[k]);
            }
        }
    }

    // ---- Phase 2 ----
    float acc0 = b2[0], acc1 = b2[1], acc2 = b2[2];  // uniform -> s_load

    const bool interior = (gr0 >= 0) & (gc0 >= 0) &
                          (gr0 + SROWS <= HH) & (gc0 + SCOLS <= WW);

    if (interior) {
        // ======== Pass A: fully unrolled, branchless, mask collection ======
        unsigned bad = 0u;
#pragma unroll
        for (int k = 0; k < 9; ++k) {
            const int kh = k / 3, kw = k - kh * 3;
            v2f pos; pos.x = (float)(ho + kh); pos.y = (float)(wo + kw);
            pos += off2[k];
            const v2f fl = __builtin_elementwise_floor(pos);
            const v2f fr = pos - fl;
            const int y0 = (int)fl.x;
            const int x0 = (int)fl.y;
            const int ly0 = y0 - gr0;
            const int lx  = x0 - gc0;

            bad |= (((unsigned)ly0 > (unsigned)(SROWS - 2)) |
                    ((unsigned)lx  > (unsigned)(SCOLS - 2))) ? (1u << k) : 0u;

            const float g00 = (1.f - fr.x) * (1.f - fr.y);
            const float g01 = (1.f - fr.x) * fr.y;
            const float g10 = fr.x * (1.f - fr.y);
            const float g11 = fr.x * fr.y;

            const int cy0 = min(max(ly0, 0), SROWS - 2);
            const int cx  = min(max(lx, 0),  SCOLS - 2);
            const int ib  = cy0 * SSTRIDE + cx;
            const v4f r0v = s_p01[ib];
            const v4f r1v = s_p01[ib + SSTRIDE];
            const v2f s0v = s_p2[ib];
            const v2f s1v = s_p2[ib + SSTRIDE];

            v2f t01 = bc2(g00) * lo2(r0v);
            t01 = fma2(bc2(g01), hi2(r0v), t01);
            t01 = fma2(bc2(g10), lo2(r1v), t01);
            t01 = fma2(bc2(g11), hi2(r1v), t01);
            float t2 = g00 * s0v.x;
            t2 = fmaf(g01, s0v.y, t2);
            t2 = fmaf(g10, s1v.x, t2);
            t2 = fmaf(g11, s1v.y, t2);

            const float v0 = t01.x, v1 = t01.y, v2v = t2;

            v2f acc01; acc01.x = acc0; acc01.y = acc1;
            acc01 = fma2(bc2(v0),  w2p[k * 3 + 0], acc01);
            acc01 = fma2(bc2(v1),  w2p[k * 3 + 1], acc01);
            acc01 = fma2(bc2(v2v), w2p[k * 3 + 2], acc01);
            acc0 = acc01.x; acc1 = acc01.y;
            acc2 = fmaf(w2s[k * 3 + 0], v0, acc2);
            acc2 = fmaf(w2s[k * 3 + 1], v1, acc2);
            acc2 = fmaf(w2s[k * 3 + 2], v2v, acc2);
        }

        // ======== Pass B: exact fixup for >8-sigma taps (execz-skipped) ====
        if (bad) {
#pragma unroll 1
            for (int k = 0; k < 9; ++k) {
                if ((bad >> k) & 1u) {
                    const int kh = k / 3, kw = k - kh * 3;
                    v2f pos; pos.x = (float)(ho + kh); pos.y = (float)(wo + kw);
                    pos += off2[k];
                    const v2f fl = __builtin_elementwise_floor(pos);
                    const v2f fr = pos - fl;
                    const int y0 = (int)fl.x;
                    const int x0 = (int)fl.y;

                    // -- wrong contribution (bit-identical ops to pass A) --
                    const int ly0 = y0 - gr0;
                    const int lx  = x0 - gc0;
                    const float a00 = (1.f - fr.x) * (1.f - fr.y);
                    const float a01 = (1.f - fr.x) * fr.y;
                    const float a10 = fr.x * (1.f - fr.y);
                    const float a11 = fr.x * fr.y;
                    const int cy0 = min(max(ly0, 0), SROWS - 2);
                    const int cx  = min(max(lx, 0),  SCOLS - 2);
                    const int ib  = cy0 * SSTRIDE + cx;
                    const v4f r0v = s_p01[ib];
                    const v4f r1v = s_p01[ib + SSTRIDE];
                    const v2f s0v = s_p2[ib];
                    const v2f s1v = s_p2[ib + SSTRIDE];
                    v2f tw01 = bc2(a00) * lo2(r0v);
                    tw01 = fma2(bc2(a01), hi2(r0v), tw01);
                    tw01 = fma2(bc2(a10), lo2(r1v), tw01);
                    tw01 = fma2(bc2(a11), hi2(r1v), tw01);
                    float tw2 = a00 * s0v.x;
                    tw2 = fmaf(a01, s0v.y, tw2);
                    tw2 = fmaf(a10, s1v.x, tw2);
                    tw2 = fmaf(a11, s1v.y, tw2);

                    // -- right contribution (exact reference semantics) --
                    const int ry0 = min(max(y0, 0), HH - 1);
                    const int ry1 = min(max(y0 + 1, 0), HH - 1);
                    const int xbs = min(max(x0, 0), WW - 2);
                    const bool vy0 = (y0 >= 0) & (y0 <= HH - 1);
                    const bool vy1 = (y0 >= -1) & (y0 <= HH - 2);
                    const bool vx0 = (x0 >= 0) & (x0 <= WW - 1);
                    const bool vx1 = (x0 >= -1) & (x0 <= WW - 2);
                    const float wy0m = vy0 ? (1.f - fr.x) : 0.f;
                    const float wy1m = vy1 ? fr.x : 0.f;
                    const float wx0m = vx0 ? (1.f - fr.y) : 0.f;
                    const float wx1m = vx1 ? fr.y : 0.f;
                    const bool selA = (x0 >= WW - 1);
                    const bool selB = (x0 >= 0);
                    const float e0 = (selA ? 0.f : wx0m) + (selB ? 0.f : wx1m);
                    const float e1 = (selA ? wx0m : 0.f) + (selB ? wx1m : 0.f);
                    const float g00 = wy0m * e0, g01 = wy0m * e1;
                    const float g10 = wy1m * e0, g11 = wy1m * e1;
                    const int o0 = ry0 * WW + xbs;
                    const int o1 = ry1 * WW + xbs;
                    v4f r0g, r1g; v2f s0g, s1g;
                    r0g.x = xp0[o0];     r0g.y = xp1[o0];
                    r0g.z = xp0[o0 + 1]; r0g.w = xp1[o0 + 1];
                    s0g.x = xp2[o0];     s0g.y = xp2[o0 + 1];
                    r1g.x = xp0[o1];     r1g.y = xp1[o1];
                    r1g.z = xp0[o1 + 1]; r1g.w = xp1[o1 + 1];
                    s1g.x = xp2[o1];     s1g.y = xp2[o1 + 1];
                    v2f tr01 = bc2(g00) * lo2(r0g);
                    tr01 = fma2(bc2(g01), hi2(r0g), tr01);
                    tr01 = fma2(bc2(g10), lo2(r1g), tr01);
                    tr01 = fma2(bc2(g11), hi2(r1g), tr01);
                    float tr2 = g00 * s0g.x;
                    tr2 = fmaf(g01, s0g.y, tr2);
                    tr2 = fmaf(g10, s1g.x, tr2);
                    tr2 = fmaf(g11, s1g.y, tr2);

                    const float d0 = tr01.x - tw01.x;
                    const float d1 = tr01.y - tw01.y;
                    const float d2 = tr2 - tw2;

                    v2f acc01; acc01.x = acc0; acc01.y = acc1;
                    acc01 = fma2(bc2(d0), w2p[k * 3 + 0], acc01);
                    acc01 = fma2(bc2(d1), w2p[k * 3 + 1], acc01);
                    acc01 = fma2(bc2(d2), w2p[k * 3 + 2], acc01);
                    acc0 = acc01.x; acc1 = acc01.y;
                    acc2 = fmaf(w2s[k * 3 + 0], d0, acc2);
                    acc2 = fmaf(w2s[k * 3 + 1], d1, acc2);
                    acc2 = fmaf(w2s[k * 3 + 2], d2, acc2);
                }
            }
        }
    } else {
        // ---- border blocks (20%): rolled exact loop ----
#pragma unroll 1
        for (int k = 0; k < 9; ++k) {
            const int kh = k / 3, kw = k - kh * 3;
            v2f pos; pos.x = (float)(ho + kh); pos.y = (float)(wo + kw);
            pos += off2[k];
            const v2f fl = __builtin_elementwise_floor(pos);
            const v2f fr = pos - fl;
            const int y0 = (int)fl.x;
            const int x0 = (int)fl.y;

            const int ry0 = min(max(y0, 0), HH - 1);
            const int ry1 = min(max(y0 + 1, 0), HH - 1);
            const int xbs = min(max(x0, 0), WW - 2);

            const bool vy0 = (y0 >= 0) & (y0 <= HH - 1);
            const bool vy1 = (y0 >= -1) & (y0 <= HH - 2);
            const bool vx0 = (x0 >= 0) & (x0 <= WW - 1);
            const bool vx1 = (x0 >= -1) & (x0 <= WW - 2);
            const float wy0m = vy0 ? (1.f - fr.x) : 0.f;
            const float wy1m = vy1 ? fr.x : 0.f;
            const float wx0m = vx0 ? (1.f - fr.y) : 0.f;
            const float wx1m = vx1 ? fr.y : 0.f;

            const bool selA = (x0 >= WW - 1);
            const bool selB = (x0 >= 0);
            const float e0 = (selA ? 0.f : wx0m) + (selB ? 0.f : wx1m);
            const float e1 = (selA ? wx0m : 0.f) + (selB ? wx1m : 0.f);
            const float g00 = wy0m * e0, g01 = wy0m * e1;
            const float g10 = wy1m * e0, g11 = wy1m * e1;

            const int ly0 = ry0 - gr0;
            const int ly1 = ry1 - gr0;
            const int lx  = xbs - gc0;
            const bool inTile = ((unsigned)ly0 <= SROWS - 1) &
                                ((unsigned)ly1 <= SROWS - 1) &
                                ((unsigned)lx  <= SCOLS - 2);

            const int cy0 = min(max(ly0, 0), SROWS - 1);
            const int cy1 = min(max(ly1, 0), SROWS - 1);
            const int cx  = min(max(lx, 0),  SCOLS - 2);
            const int ib0 = cy0 * SSTRIDE + cx;
            const int ib1 = cy1 * SSTRIDE + cx;
            v4f r0v = s_p01[ib0];
            v4f r1v = s_p01[ib1];
            v2f s0v = s_p2[ib0];
            v2f s1v = s_p2[ib1];

            if (!inTile) {
                const int o0 = ry0 * WW + xbs;
                const int o1 = ry1 * WW + xbs;
                r0v.x = xp0[o0];     r0v.y = xp1[o0];
                r0v.z = xp0[o0 + 1]; r0v.w = xp1[o0 + 1];
                s0v.x = xp2[o0];     s0v.y = xp2[o0 + 1];
                r1v.x = xp0[o1];     r1v.y = xp1[o1];
                r1v.z = xp0[o1 + 1]; r1v.w = xp1[o1 + 1];
                s1v.x = xp2[o1];     s1v.y = xp2[o1 + 1];
            }

            v2f t01 = bc2(g00) * lo2(r0v);
            t01 = fma2(bc2(g01), hi2(r0v), t01);
            t01 = fma2(bc2(g10), lo2(r1v), t01);
            t01 = fma2(bc2(g11), hi2(r1v), t01);
            float t2 = g00 * s0v.x;
            t2 = fmaf(g01, s0v.y, t2);
            t2 = fmaf(g10, s1v.x, t2);
            t2 = fmaf(g11, s1v.y, t2);

            const float v0 = t01.x, v1 = t01.y, v2v = t2;

            v2f acc01; acc01.x = acc0; acc01.y = acc1;
            acc01 = fma2(bc2(v0),  w2p[k * 3 + 0], acc01);
            acc01 = fma2(bc2(v1),  w2p[k * 3 + 1], acc01);
            acc01 = fma2(bc2(v2v), w2p[k * 3 + 2], acc01);
            acc0 = acc01.x; acc1 = acc01.y;
            acc2 = fmaf(w2s[k * 3 + 0], v0, acc2);
            acc2 = fmaf(w2s[k * 3 + 1], v1, acc2);
            acc2 = fmaf(w2s[k * 3 + 2], v2v, acc2);
        }
    }

    const long obase = ((long)(b * 3) * HO + ho) * WO + wo;
    __builtin_nontemporal_store(acc0, out + obase);
    __builtin_nontemporal_store(acc1, out + obase + (long)HO * WO);
    __builtin_nontemporal_store(acc2, out + obase + 2L * HO * WO);
}

extern "C" void kernel_launch(void* const* d_in, const int* in_sizes, int n_in,
                              void* d_out, int out_size, void* d_ws, size_t ws_size,
                              hipStream_t stream) {
    const float* x  = (const float*)d_in[0];
    const float* w1 = (const float*)d_in[1];
    const float* b1 = (const float*)d_in[2];
    const float* w2 = (const float*)d_in[3];
    const float* b2 = (const float*)d_in[4];
    float* out = (float*)d_out;
    float* ws  = (float*)d_ws;

    const int blocks = TILES_X * TILES_Y * BB;   // 12*48*8 = 4608
    const bool use_ws = (d_ws != nullptr) && (ws_size >= WS_FLOATS * sizeof(float));

    if (use_ws) {
        prep_weights<<<1, 512, 0, stream>>>(w1, w2, ws);
        deform_tiled<true><<<blocks, 256, 0, stream>>>(x, w1, b1, w2, b2, ws, out);
    } else {
        deform_tiled<false><<<blocks, 256, 0, stream>>>(x, w1, b1, w2, b2, nullptr, out);
    }
}